// Round 1
// baseline (303.144 us; speedup 1.0000x reference)
//
#include <hip/hip_runtime.h>
#include <hip/hip_bf16.h>

typedef __attribute__((ext_vector_type(8))) short short8;
typedef __attribute__((ext_vector_type(4))) float f32x4;

static constexpr int NN = 2048, DD = 512;
static constexpr float SCALE = 0.088388347648318447f;   // 128^-0.5
static constexpr float ENT_SCALE = 0.1f / 32768.0f;     // mean over b*h*n rows, * SPARSITY_WEIGHT

__device__ __forceinline__ short f2bf(float f) {
  __hip_bfloat16 h = __float2bfloat16(f);
  return *reinterpret_cast<short*>(&h);
}

__device__ __forceinline__ void async_cp16(const void* g, void* l) {
  __builtin_amdgcn_global_load_lds((const __attribute__((address_space(1))) void*)g,
                                   (__attribute__((address_space(3))) void*)l, 16, 0, 0);
}

// ---------------- LN + FiLM -> bf16 ----------------
__global__ __launch_bounds__(256) void ln_film_k(
    const float* __restrict__ x, const float* __restrict__ gamma,
    const float* __restrict__ beta, const float* __restrict__ lnw,
    const float* __restrict__ lnb, short* __restrict__ xn) {
  const int wave = threadIdx.x >> 6, lane = threadIdx.x & 63;
  const int row = blockIdx.x * 4 + wave;   // 0..8191
  const int b = row >> 11;
  const float4* xr = reinterpret_cast<const float4*>(x + (size_t)row * DD);
  float4 u = xr[lane * 2], v = xr[lane * 2 + 1];
  float s  = u.x + u.y + u.z + u.w + v.x + v.y + v.z + v.w;
  float ss = u.x*u.x + u.y*u.y + u.z*u.z + u.w*u.w + v.x*v.x + v.y*v.y + v.z*v.z + v.w*v.w;
  #pragma unroll
  for (int m = 1; m < 64; m <<= 1) { s += __shfl_xor(s, m); ss += __shfl_xor(ss, m); }
  const float mu = s * (1.0f / DD);
  const float rs = rsqrtf(ss * (1.0f / DD) - mu * mu + 1e-5f);
  const int c0 = lane * 8;
  float vals[8] = {u.x,u.y,u.z,u.w,v.x,v.y,v.z,v.w};
  short8 o;
  #pragma unroll
  for (int i = 0; i < 8; ++i) {
    const int c = c0 + i;
    const float t = (vals[i] - mu) * rs * lnw[c] + lnb[c];
    o[i] = f2bf(gamma[b * DD + c] * t + beta[b * DD + c]);
  }
  *reinterpret_cast<short8*>(xn + (size_t)row * DD + c0) = o;
}

// ---------------- transpose + cast weight to B^T bf16 ----------------
__global__ void transpose_bf16_k(const float* __restrict__ w, short* __restrict__ wt,
                                 int K, int Nc) {
  const int id = blockIdx.x * 256 + threadIdx.x;
  if (id >= K * Nc) return;
  const int k = id / Nc, c = id - k * Nc;
  wt[(size_t)c * K + k] = f2bf(w[id]);
}

// ---------------- 128x128 tile GEMM: C[M,NT] = A[M,512] * Bt[NT,512]^T ----------------
template<int NT, bool BF16OUT>
__global__ __launch_bounds__(256) void gemm_bt_k(
    const short* __restrict__ A, const short* __restrict__ Bt, void* __restrict__ C) {
  constexpr int K = 512;
  __shared__ char lds[32768];
  char* const Alds = lds;
  char* const Blds = lds + 16384;
  constexpr int nTiles = NT / 128;
  const int m0 = (blockIdx.x / nTiles) * 128;
  const int n0 = (blockIdx.x % nTiles) * 128;
  const int tid = threadIdx.x, wave = tid >> 6, lane = tid & 63;
  const int wm = wave >> 1, wn = wave & 1;
  const int lg = lane >> 4, li = lane & 15;
  f32x4 acc[4][4] = {};
  for (int kt = 0; kt < K / 64; ++kt) {
    __syncthreads();
    #pragma unroll
    for (int i = 0; i < 4; ++i) {
      const int chunk = wave * 4 + i;
      const int m = chunk * 8 + (lane >> 3);
      const int cs = ((lane & 7) * 16) ^ ((m & 7) << 4);   // inverse-swizzled source (rule #21)
      async_cp16((const char*)A  + ((size_t)(m0 + m) * K + kt * 64) * 2 + cs, Alds + chunk * 1024);
      async_cp16((const char*)Bt + ((size_t)(n0 + m) * K + kt * 64) * 2 + cs, Blds + chunk * 1024);
    }
    __syncthreads();
    #pragma unroll
    for (int ks = 0; ks < 2; ++ks) {
      const int kb = ks * 64 + lg * 16;
      short8 af[4], bfr[4];
      #pragma unroll
      for (int t = 0; t < 4; ++t) {
        const int r = wm * 64 + t * 16 + li;
        af[t]  = *reinterpret_cast<const short8*>(Alds + r * 128 + (kb ^ ((r & 7) << 4)));
        const int c = wn * 64 + t * 16 + li;
        bfr[t] = *reinterpret_cast<const short8*>(Blds + c * 128 + (kb ^ ((c & 7) << 4)));
      }
      #pragma unroll
      for (int mt = 0; mt < 4; ++mt)
        #pragma unroll
        for (int nt = 0; nt < 4; ++nt)
          acc[mt][nt] = __builtin_amdgcn_mfma_f32_16x16x32_bf16(af[mt], bfr[nt], acc[mt][nt], 0, 0, 0);
    }
  }
  #pragma unroll
  for (int mt = 0; mt < 4; ++mt) {
    #pragma unroll
    for (int nt = 0; nt < 4; ++nt) {
      const int row = m0 + wm * 64 + mt * 16 + lg * 4;
      const int col = n0 + wn * 64 + nt * 16 + li;
      #pragma unroll
      for (int r = 0; r < 4; ++r) {
        if (BF16OUT)
          reinterpret_cast<short*>(C)[(size_t)(row + r) * NT + col] = f2bf(acc[mt][nt][r]);
        else
          reinterpret_cast<float*>(C)[(size_t)(row + r) * NT + col] = acc[mt][nt][r];
      }
    }
  }
}

// ---------------- fused flash attention + entropy ----------------
__global__ __launch_bounds__(256) void attn_k(
    const short* __restrict__ qkv, const float* __restrict__ alibi,
    short* __restrict__ ao, float* __restrict__ ent) {
  __shared__ char Klds[16384];
  __shared__ char Vlds[16384];
  __shared__ short Plds[4][1024];
  const int qt = blockIdx.x, bh = blockIdx.y;
  const int b = bh >> 2, h = bh & 3;
  const int tid = threadIdx.x, wave = tid >> 6, lane = tid & 63;
  const int lg = lane >> 4, li = lane & 15;
  short* const Vs = reinterpret_cast<short*>(Vlds);

  // Q fragments held in registers for the whole block
  const int qrow = qt * 64 + wave * 16 + li;   // within batch
  const char* qptr = (const char*)qkv + ((size_t)(b * NN + qrow) * 1536 + h * 128) * 2;
  short8 qf[4];
  #pragma unroll
  for (int kq = 0; kq < 4; ++kq)
    qf[kq] = *reinterpret_cast<const short8*>(qptr + kq * 64 + lg * 16);

  f32x4 oacc[8] = {};
  float mrow[4], lrow[4], trow[4];
  #pragma unroll
  for (int r = 0; r < 4; ++r) { mrow[r] = -INFINITY; lrow[r] = 0.f; trow[r] = 0.f; }
  const float* arow = alibi + ((size_t)b * NN + (qt * 64 + wave * 16 + lg * 4)) * NN;

  for (int kt = 0; kt < 32; ++kt) {
    __syncthreads();
    // K tile: global_load_lds, linear dest + inverse-swizzled source
    #pragma unroll
    for (int i = 0; i < 4; ++i) {
      const int chunk = wave * 4 + i;
      const int mloc = chunk * 4 + lg;
      const int cs = (li * 16) ^ ((mloc & 7) << 4);
      const size_t src = ((size_t)(b * NN + kt * 64 + mloc) * 1536 + 512 + h * 128) * 2 + cs;
      async_cp16((const char*)qkv + src, Klds + chunk * 1024);
    }
    // V tile: register-staged transpose into LDS (Vt[dh][key], swizzled)
    #pragma unroll
    for (int p = 0; p < 4; ++p) {
      const int dh0 = wave * 8 + p * 32;
      const int jv = lane;
      short8 vv = *reinterpret_cast<const short8*>(
          (const char*)qkv + ((size_t)(b * NN + kt * 64 + jv) * 1536 + 1024 + h * 128 + dh0) * 2);
      #pragma unroll
      for (int i2 = 0; i2 < 8; ++i2) {
        const int dh = dh0 + i2;
        Vs[dh * 64 + (jv ^ ((dh & 7) << 3))] = vv[i2];
      }
    }
    __syncthreads();
    // QK^T: 16 MFMA per wave
    f32x4 sacc[4] = {};
    #pragma unroll
    for (int ct = 0; ct < 4; ++ct) {
      const int key = ct * 16 + li;
      #pragma unroll
      for (int kq = 0; kq < 4; ++kq) {
        short8 kf = *reinterpret_cast<const short8*>(
            Klds + key * 256 + ((kq * 64 + lg * 16) ^ ((key & 7) << 4)));
        sacc[ct] = __builtin_amdgcn_mfma_f32_16x16x32_bf16(qf[kq], kf, sacc[ct], 0, 0, 0);
      }
    }
    // online softmax + entropy accumulators (H = m + log l - t/l)
    float sv[4][4];
    #pragma unroll
    for (int ct = 0; ct < 4; ++ct)
      #pragma unroll
      for (int r = 0; r < 4; ++r)
        sv[ct][r] = sacc[ct][r] * SCALE + arow[(size_t)r * NN + kt * 64 + ct * 16 + li];
    #pragma unroll
    for (int r = 0; r < 4; ++r) {
      float mx = fmaxf(fmaxf(sv[0][r], sv[1][r]), fmaxf(sv[2][r], sv[3][r]));
      #pragma unroll
      for (int msk = 1; msk < 16; msk <<= 1) mx = fmaxf(mx, __shfl_xor(mx, msk, 16));
      const float newm = fmaxf(mrow[r], mx);
      const float fsc = __expf(mrow[r] - newm);
      float ps[4], lsum = 0.f, tsum = 0.f;
      #pragma unroll
      for (int ct = 0; ct < 4; ++ct) {
        ps[ct] = __expf(sv[ct][r] - newm);
        lsum += ps[ct];
        tsum += ps[ct] * sv[ct][r];
      }
      #pragma unroll
      for (int msk = 1; msk < 16; msk <<= 1) {
        lsum += __shfl_xor(lsum, msk, 16);
        tsum += __shfl_xor(tsum, msk, 16);
      }
      lrow[r] = lrow[r] * fsc + lsum;
      trow[r] = trow[r] * fsc + tsum;
      mrow[r] = newm;
      #pragma unroll
      for (int nt = 0; nt < 8; ++nt) oacc[nt][r] *= fsc;
      const int prow = lg * 4 + r;
      #pragma unroll
      for (int ct = 0; ct < 4; ++ct)
        Plds[wave][prow * 64 + ((ct * 16 + li) ^ ((prow & 7) << 3))] = f2bf(ps[ct]);
    }
    // PV: 16 MFMA per wave
    #pragma unroll
    for (int ks = 0; ks < 2; ++ks) {
      const int kb = ks * 64 + lg * 16;
      short8 pa = *reinterpret_cast<const short8*>(
          (const char*)Plds[wave] + li * 128 + (kb ^ ((li & 7) << 4)));
      #pragma unroll
      for (int nt = 0; nt < 8; ++nt) {
        const int dh = nt * 16 + li;
        short8 vb = *reinterpret_cast<const short8*>(
            Vlds + dh * 128 + (kb ^ ((dh & 7) << 4)));
        oacc[nt] = __builtin_amdgcn_mfma_f32_16x16x32_bf16(pa, vb, oacc[nt], 0, 0, 0);
      }
    }
  }
  // epilogue: normalized attention output (bf16) + entropy atomics
  const int orow = b * NN + qt * 64 + wave * 16 + lg * 4;
  #pragma unroll
  for (int nt = 0; nt < 8; ++nt)
    #pragma unroll
    for (int r = 0; r < 4; ++r)
      ao[(size_t)(orow + r) * DD + h * 128 + nt * 16 + li] = f2bf(oacc[nt][r] / lrow[r]);
  if (li == 0) {
    float e = 0.f;
    #pragma unroll
    for (int r = 0; r < 4; ++r) e += mrow[r] + logf(lrow[r]) - trow[r] / lrow[r];
    atomicAdd(ent, e * ENT_SCALE);
  }
}

extern "C" void kernel_launch(void* const* d_in, const int* in_sizes, int n_in,
                              void* d_out, int out_size, void* d_ws, size_t ws_size,
                              hipStream_t stream) {
  const float* x     = (const float*)d_in[0];
  const float* alibi = (const float*)d_in[1];
  const float* gamma = (const float*)d_in[2];
  const float* beta  = (const float*)d_in[3];
  const float* lnw   = (const float*)d_in[4];
  const float* lnb   = (const float*)d_in[5];
  const float* wqkv  = (const float*)d_in[6];
  const float* wout  = (const float*)d_in[7];
  float* out = (float*)d_out;

  char* ws = (char*)d_ws;
  short* xn    = (short*)(ws);                      // 8192*512 bf16 (8 MB)
  short* wqkvT = (short*)(ws + 8388608);            // 1536*512 bf16
  short* woutT = (short*)(ws + 8388608 + 1572864);  // 512*512 bf16
  short* qkv   = (short*)(ws + 10485760);           // 8192*1536 bf16 (24 MB)
  short* ao    = (short*)(ws);                      // reuse xn region (consumed by GEMM1)

  hipMemsetAsync(out + 4194304, 0, 4, stream);      // zero the entropy accumulator (d_out last elem)
  ln_film_k<<<2048, 256, 0, stream>>>(x, gamma, beta, lnw, lnb, xn);
  transpose_bf16_k<<<(512 * 1536 + 255) / 256, 256, 0, stream>>>(wqkv, wqkvT, 512, 1536);
  transpose_bf16_k<<<(512 * 512 + 255) / 256, 256, 0, stream>>>(wout, woutT, 512, 512);
  gemm_bt_k<1536, true><<<64 * 12, 256, 0, stream>>>(xn, wqkvT, qkv);
  attn_k<<<dim3(32, 16), 256, 0, stream>>>(qkv, alibi, ao, out + 4194304);
  gemm_bt_k<512, false><<<64 * 4, 256, 0, stream>>>(ao, woutT, out);
}

// Round 2
// 269.537 us; speedup vs baseline: 1.1247x; 1.1247x over previous
//
#include <hip/hip_runtime.h>
#include <hip/hip_bf16.h>

typedef __attribute__((ext_vector_type(8))) short short8;
typedef __attribute__((ext_vector_type(4))) short short4_t;
typedef __attribute__((ext_vector_type(4))) float f32x4;

static constexpr int NN = 2048, DD = 512;
static constexpr float SCALE = 0.088388347648318447f;   // 128^-0.5
static constexpr float ENT_SCALE = 0.1f / 32768.0f;     // mean over b*h*n rows * SPARSITY_WEIGHT

__device__ __forceinline__ short f2bf(float f) {
  __hip_bfloat16 h = __float2bfloat16(f);
  return *reinterpret_cast<short*>(&h);
}

__device__ __forceinline__ void async_cp16(const void* g, void* l) {
  __builtin_amdgcn_global_load_lds((const __attribute__((address_space(1))) void*)g,
                                   (__attribute__((address_space(3))) void*)l, 16, 0, 0);
}

// ---------------- LN + FiLM -> bf16 ----------------
__global__ __launch_bounds__(256) void ln_film_k(
    const float* __restrict__ x, const float* __restrict__ gamma,
    const float* __restrict__ beta, const float* __restrict__ lnw,
    const float* __restrict__ lnb, short* __restrict__ xn) {
  const int wave = threadIdx.x >> 6, lane = threadIdx.x & 63;
  const int row = blockIdx.x * 4 + wave;   // 0..8191
  const int b = row >> 11;
  const float4* xr = reinterpret_cast<const float4*>(x + (size_t)row * DD);
  float4 u = xr[lane * 2], v = xr[lane * 2 + 1];
  float s  = u.x + u.y + u.z + u.w + v.x + v.y + v.z + v.w;
  float ss = u.x*u.x + u.y*u.y + u.z*u.z + u.w*u.w + v.x*v.x + v.y*v.y + v.z*v.z + v.w*v.w;
  #pragma unroll
  for (int m = 1; m < 64; m <<= 1) { s += __shfl_xor(s, m); ss += __shfl_xor(ss, m); }
  const float mu = s * (1.0f / DD);
  const float rs = rsqrtf(ss * (1.0f / DD) - mu * mu + 1e-5f);
  const int c0 = lane * 8;
  float vals[8] = {u.x,u.y,u.z,u.w,v.x,v.y,v.z,v.w};
  short8 o;
  #pragma unroll
  for (int i = 0; i < 8; ++i) {
    const int c = c0 + i;
    const float t = (vals[i] - mu) * rs * lnw[c] + lnb[c];
    o[i] = f2bf(gamma[b * DD + c] * t + beta[b * DD + c]);
  }
  *reinterpret_cast<short8*>(xn + (size_t)row * DD + c0) = o;
}

// ---------------- transpose + cast weight to B^T bf16 ----------------
__global__ void transpose_bf16_k(const float* __restrict__ w, short* __restrict__ wt,
                                 int K, int Nc) {
  const int id = blockIdx.x * 256 + threadIdx.x;
  if (id >= K * Nc) return;
  const int k = id / Nc, c = id - k * Nc;
  wt[(size_t)c * K + k] = f2bf(w[id]);
}

// ---------------- BMx128 tile GEMM (2-phase dbuf): C = A[M,512] * Bt[N,512]^T ----------------
template<int BM, int NT, bool BF16OUT>
__global__ __launch_bounds__(256) void gemm_bt_k(
    const short* __restrict__ A, const short* __restrict__ Bt, void* __restrict__ C) {
  constexpr int K = 512;
  constexpr int ABYTES = BM * 128;              // one A tile (row = 64 bf16 = 128B)
  __shared__ char lds[2 * ABYTES + 32768];
  constexpr int nTiles = NT / 128;
  const int m0 = (blockIdx.x / nTiles) * BM;
  const int n0 = (blockIdx.x % nTiles) * 128;
  const int tid = threadIdx.x, wave = tid >> 6, lane = tid & 63;
  const int wm = wave >> 1, wn = wave & 1;
  const int lg = lane >> 4, li = lane & 15;
  constexpr int MT = BM / 32;
  f32x4 acc[MT][4] = {};

  auto stage = [&](int buf, int kt) {
    #pragma unroll
    for (int t = 0; t < BM / 32; ++t) {
      const int dbase = t * 4096 + wave * 1024;          // wave-uniform LDS base
      const int m = (dbase >> 7) + (lane >> 3);
      const int cs = ((lane & 7) * 16) ^ ((m & 7) << 4); // inverse-swizzled source
      async_cp16((const char*)A + ((size_t)(m0 + m) * K + kt * 64) * 2 + cs,
                 lds + buf * ABYTES + dbase);
    }
    #pragma unroll
    for (int t = 0; t < 4; ++t) {
      const int dbase = t * 4096 + wave * 1024;
      const int n = (dbase >> 7) + (lane >> 3);
      const int cs = ((lane & 7) * 16) ^ ((n & 7) << 4);
      async_cp16((const char*)Bt + ((size_t)(n0 + n) * K + kt * 64) * 2 + cs,
                 lds + 2 * ABYTES + buf * 16384 + dbase);
    }
  };

  stage(0, 0);
  __syncthreads();
  for (int kt = 0; kt < 8; ++kt) {
    const int cur = kt & 1;
    if (kt < 7) stage(cur ^ 1, kt + 1);
    const char* Al = lds + cur * ABYTES;
    const char* Bl = lds + 2 * ABYTES + cur * 16384;
    #pragma unroll
    for (int ks = 0; ks < 2; ++ks) {
      const int kb = ks * 64 + lg * 16;
      short8 af[MT], bfr[4];
      #pragma unroll
      for (int t = 0; t < MT; ++t) {
        const int r = wm * (BM / 2) + t * 16 + li;
        af[t] = *reinterpret_cast<const short8*>(Al + r * 128 + (kb ^ ((r & 7) << 4)));
      }
      #pragma unroll
      for (int t = 0; t < 4; ++t) {
        const int c = wn * 64 + t * 16 + li;
        bfr[t] = *reinterpret_cast<const short8*>(Bl + c * 128 + (kb ^ ((c & 7) << 4)));
      }
      #pragma unroll
      for (int mt = 0; mt < MT; ++mt)
        #pragma unroll
        for (int nt = 0; nt < 4; ++nt)
          acc[mt][nt] = __builtin_amdgcn_mfma_f32_16x16x32_bf16(af[mt], bfr[nt], acc[mt][nt], 0, 0, 0);
    }
    __syncthreads();
  }
  #pragma unroll
  for (int mt = 0; mt < MT; ++mt) {
    #pragma unroll
    for (int nt = 0; nt < 4; ++nt) {
      const int row = m0 + wm * (BM / 2) + mt * 16 + lg * 4;
      const int col = n0 + wn * 64 + nt * 16 + li;
      #pragma unroll
      for (int r = 0; r < 4; ++r) {
        if (BF16OUT)
          reinterpret_cast<short*>(C)[(size_t)(row + r) * NT + col] = f2bf(acc[mt][nt][r]);
        else
          reinterpret_cast<float*>(C)[(size_t)(row + r) * NT + col] = acc[mt][nt][r];
      }
    }
  }
}

// ---------------- fused flash attention + entropy (swapped operands, 2-phase) ----------------
__global__ __launch_bounds__(256) void attn_k(
    const short* __restrict__ qkv, const float* __restrict__ alibi,
    short* __restrict__ ao, float* __restrict__ ent) {
  __shared__ char lds[73728];   // K dbuf 32K | V dbuf 32K | P 4x2K
  const int qt = blockIdx.x, bh = blockIdx.y;
  const int b = bh >> 2, h = bh & 3;
  const int tid = threadIdx.x, wave = tid >> 6, lane = tid & 63;
  const int lg = lane >> 4, li = lane & 15;
  char* const Pbase = lds + 65536 + wave * 2048;

  const int qrow = qt * 64 + wave * 16 + li;          // this lane's q-row (within batch)
  const char* qptr = (const char*)qkv + ((size_t)(b * NN + qrow) * 1536 + h * 128) * 2;
  short8 qf[4];
  #pragma unroll
  for (int kq = 0; kq < 4; ++kq)
    qf[kq] = *reinterpret_cast<const short8*>(qptr + kq * 64 + lg * 16);

  f32x4 oacc[8] = {};
  float mrow = -INFINITY, lrow = 0.f, trow = 0.f;     // lane-local online-softmax state (q = li)
  const float* arow = alibi + (size_t)(b * NN + qrow) * NN;

  auto stageK = [&](int buf, int kt) {
    #pragma unroll
    for (int i = 0; i < 4; ++i) {
      const int chunk = wave * 4 + i;
      const int mloc = chunk * 4 + lg;
      const int cs = (li * 16) ^ ((mloc & 7) << 4);
      async_cp16((const char*)qkv + ((size_t)(b * NN + kt * 64 + mloc) * 1536 + 512 + h * 128) * 2 + cs,
                 lds + buf * 16384 + chunk * 1024);
    }
  };
  auto loadV = [&](int kt, short8* vv) {
    #pragma unroll
    for (int p = 0; p < 4; ++p)
      vv[p] = *reinterpret_cast<const short8*>(
          (const char*)qkv + ((size_t)(b * NN + kt * 64 + lane) * 1536 + 1024 + h * 128 + wave * 8 + p * 32) * 2);
  };
  auto writeV = [&](int buf, const short8* vv) {
    short* Vp = reinterpret_cast<short*>(lds + 32768 + buf * 16384);
    #pragma unroll
    for (int p = 0; p < 4; ++p)
      #pragma unroll
      for (int i2 = 0; i2 < 8; ++i2) {
        const int dh = wave * 8 + p * 32 + i2;
        Vp[dh * 64 + (lane ^ ((dh & 7) << 3))] = vv[p][i2];
      }
  };
  auto loadA = [&](int kt, float4* ab) {
    #pragma unroll
    for (int ct = 0; ct < 4; ++ct)
      ab[ct] = *reinterpret_cast<const float4*>(arow + kt * 64 + ct * 16 + lg * 4);
  };

  short8 vv[4]; float4 ab[4];
  stageK(0, 0); loadV(0, vv); loadA(0, ab);
  writeV(0, vv);
  __syncthreads();

  for (int kt = 0; kt < 32; ++kt) {
    const int cur = kt & 1, nxt = cur ^ 1;
    short8 vvn[4]; float4 abn[4];
    if (kt < 31) { stageK(nxt, kt + 1); loadV(kt + 1, vvn); loadA(kt + 1, abn); }

    // QK^T swapped: D[key][q], q = li lane-local
    f32x4 sacc[4] = {};
    const char* Kl = lds + cur * 16384;
    #pragma unroll
    for (int ct = 0; ct < 4; ++ct) {
      const int key = ct * 16 + li;
      #pragma unroll
      for (int kq = 0; kq < 4; ++kq) {
        short8 kf = *reinterpret_cast<const short8*>(
            Kl + key * 256 + ((kq * 64 + lg * 16) ^ ((key & 7) << 4)));
        sacc[ct] = __builtin_amdgcn_mfma_f32_16x16x32_bf16(kf, qf[kq], sacc[ct], 0, 0, 0);
      }
    }
    // softmax: 16 in-lane scores (keys ct*16+lg*4+r for q=li), reduce over 4 lg-lanes
    float sv[4][4], p[4][4];
    #pragma unroll
    for (int ct = 0; ct < 4; ++ct) {
      sv[ct][0] = sacc[ct][0] * SCALE + ab[ct].x;
      sv[ct][1] = sacc[ct][1] * SCALE + ab[ct].y;
      sv[ct][2] = sacc[ct][2] * SCALE + ab[ct].z;
      sv[ct][3] = sacc[ct][3] * SCALE + ab[ct].w;
    }
    float mx = sv[0][0];
    #pragma unroll
    for (int ct = 0; ct < 4; ++ct)
      #pragma unroll
      for (int r = 0; r < 4; ++r) mx = fmaxf(mx, sv[ct][r]);
    mx = fmaxf(mx, __shfl_xor(mx, 16));
    mx = fmaxf(mx, __shfl_xor(mx, 32));
    const bool resc = !__all(mx <= mrow + 8.0f);     // defer-max (T13)
    float newm = mrow, fsc = 1.0f;
    if (resc) { newm = fmaxf(mrow, mx); fsc = __expf(mrow - newm); }
    float lsum = 0.f, tsum = 0.f;
    #pragma unroll
    for (int ct = 0; ct < 4; ++ct)
      #pragma unroll
      for (int r = 0; r < 4; ++r) {
        p[ct][r] = __expf(sv[ct][r] - newm);
        lsum += p[ct][r];
        tsum = fmaf(p[ct][r], sv[ct][r], tsum);
      }
    lsum += __shfl_xor(lsum, 16); lsum += __shfl_xor(lsum, 32);
    tsum += __shfl_xor(tsum, 16); tsum += __shfl_xor(tsum, 32);
    if (resc) {
      lrow = lrow * fsc + lsum; trow = trow * fsc + tsum; mrow = newm;
      #pragma unroll
      for (int nt = 0; nt < 8; ++nt) oacc[nt] *= fsc;
    } else { lrow += lsum; trow += tsum; }
    // P[q=li][key] -> LDS (short4 packed, swizzled)
    #pragma unroll
    for (int ct = 0; ct < 4; ++ct) {
      short4_t pw;
      #pragma unroll
      for (int r = 0; r < 4; ++r) pw[r] = f2bf(p[ct][r]);
      *reinterpret_cast<short4_t*>(Pbase + li * 128 + ((ct * 32 + lg * 8) ^ ((li & 7) << 4))) = pw;
    }
    // PV swapped: D[dh][q], q = li lane-local
    const char* Vl = lds + 32768 + cur * 16384;
    #pragma unroll
    for (int ks = 0; ks < 2; ++ks) {
      const int kb = ks * 64 + lg * 16;
      short8 pa = *reinterpret_cast<const short8*>(Pbase + li * 128 + (kb ^ ((li & 7) << 4)));
      #pragma unroll
      for (int nt = 0; nt < 8; ++nt) {
        const int dh = nt * 16 + li;
        short8 vb = *reinterpret_cast<const short8*>(Vl + dh * 128 + (kb ^ ((dh & 7) << 4)));
        oacc[nt] = __builtin_amdgcn_mfma_f32_16x16x32_bf16(vb, pa, oacc[nt], 0, 0, 0);
      }
    }
    if (kt < 31) {
      writeV(nxt, vvn);
      #pragma unroll
      for (int ct = 0; ct < 4; ++ct) ab[ct] = abn[ct];
    }
    __syncthreads();
  }

  // epilogue: O[q=li][dh = nt*16+lg*4+r], normalized; packed 8B stores
  const float invl = 1.0f / lrow;
  #pragma unroll
  for (int nt = 0; nt < 8; ++nt) {
    short4_t ow;
    #pragma unroll
    for (int r = 0; r < 4; ++r) ow[r] = f2bf(oacc[nt][r] * invl);
    *reinterpret_cast<short4_t*>(ao + (size_t)(b * NN + qrow) * DD + h * 128 + nt * 16 + lg * 4) = ow;
  }
  // entropy: H = m + log l - t/l per q-row (lg==0 lanes own the 16 rows)
  float e = (lg == 0) ? (mrow + logf(lrow) - trow * invl) : 0.f;
  #pragma unroll
  for (int m = 1; m < 64; m <<= 1) e += __shfl_xor(e, m);
  if (lane == 0) atomicAdd(ent, e * ENT_SCALE);
}

extern "C" void kernel_launch(void* const* d_in, const int* in_sizes, int n_in,
                              void* d_out, int out_size, void* d_ws, size_t ws_size,
                              hipStream_t stream) {
  const float* x     = (const float*)d_in[0];
  const float* alibi = (const float*)d_in[1];
  const float* gamma = (const float*)d_in[2];
  const float* beta  = (const float*)d_in[3];
  const float* lnw   = (const float*)d_in[4];
  const float* lnb   = (const float*)d_in[5];
  const float* wqkv  = (const float*)d_in[6];
  const float* wout  = (const float*)d_in[7];
  float* out = (float*)d_out;

  char* ws = (char*)d_ws;
  short* xn    = (short*)(ws);                      // 8192*512 bf16 (8 MB)
  short* wqkvT = (short*)(ws + 8388608);            // 1536*512 bf16
  short* woutT = (short*)(ws + 8388608 + 1572864);  // 512*512 bf16
  short* qkv   = (short*)(ws + 10485760);           // 8192*1536 bf16 (24 MB)
  short* ao    = (short*)(ws);                      // reuse xn region (consumed by GEMM1)

  hipMemsetAsync(out + 4194304, 0, 4, stream);      // zero entropy accumulator
  ln_film_k<<<2048, 256, 0, stream>>>(x, gamma, beta, lnw, lnb, xn);
  transpose_bf16_k<<<(512 * 1536 + 255) / 256, 256, 0, stream>>>(wqkv, wqkvT, 512, 1536);
  transpose_bf16_k<<<(512 * 512 + 255) / 256, 256, 0, stream>>>(wout, woutT, 512, 512);
  gemm_bt_k<128, 1536, true><<<64 * 12, 256, 0, stream>>>(xn, wqkvT, qkv);
  attn_k<<<dim3(32, 16), 256, 0, stream>>>(qkv, alibi, ao, out + 4194304);
  gemm_bt_k<64, 512, false><<<128 * 4, 256, 0, stream>>>(ao, woutT, out);
}

// Round 3
// 247.056 us; speedup vs baseline: 1.2270x; 1.0910x over previous
//
#include <hip/hip_runtime.h>
#include <hip/hip_bf16.h>

typedef __attribute__((ext_vector_type(8))) short short8;
typedef __attribute__((ext_vector_type(4))) short short4_t;
typedef __attribute__((ext_vector_type(4))) float f32x4;

static constexpr int NN = 2048, DD = 512;
static constexpr float SCALE = 0.088388347648318447f;   // 128^-0.5
static constexpr float ENT_SCALE = 0.1f / 32768.0f;     // mean over b*h*n rows * SPARSITY_WEIGHT

__device__ __forceinline__ short f2bf(float f) {
  __hip_bfloat16 h = __float2bfloat16(f);
  return *reinterpret_cast<short*>(&h);
}

__device__ __forceinline__ void async_cp16(const void* g, void* l) {
  __builtin_amdgcn_global_load_lds((const __attribute__((address_space(1))) void*)g,
                                   (__attribute__((address_space(3))) void*)l, 16, 0, 0);
}

// ---------------- LN + FiLM -> bf16 ----------------
__global__ __launch_bounds__(256) void ln_film_k(
    const float* __restrict__ x, const float* __restrict__ gamma,
    const float* __restrict__ beta, const float* __restrict__ lnw,
    const float* __restrict__ lnb, short* __restrict__ xn) {
  const int wave = threadIdx.x >> 6, lane = threadIdx.x & 63;
  const int row = blockIdx.x * 4 + wave;   // 0..8191
  const int b = row >> 11;
  const float4* xr = reinterpret_cast<const float4*>(x + (size_t)row * DD);
  float4 u = xr[lane * 2], v = xr[lane * 2 + 1];
  float s  = u.x + u.y + u.z + u.w + v.x + v.y + v.z + v.w;
  float ss = u.x*u.x + u.y*u.y + u.z*u.z + u.w*u.w + v.x*v.x + v.y*v.y + v.z*v.z + v.w*v.w;
  #pragma unroll
  for (int m = 1; m < 64; m <<= 1) { s += __shfl_xor(s, m); ss += __shfl_xor(ss, m); }
  const float mu = s * (1.0f / DD);
  const float rs = rsqrtf(ss * (1.0f / DD) - mu * mu + 1e-5f);
  const int c0 = lane * 8;
  float vals[8] = {u.x,u.y,u.z,u.w,v.x,v.y,v.z,v.w};
  short8 o;
  #pragma unroll
  for (int i = 0; i < 8; ++i) {
    const int c = c0 + i;
    const float t = (vals[i] - mu) * rs * lnw[c] + lnb[c];
    o[i] = f2bf(gamma[b * DD + c] * t + beta[b * DD + c]);
  }
  *reinterpret_cast<short8*>(xn + (size_t)row * DD + c0) = o;
}

// ---------------- both weight transposes in one launch ----------------
__global__ void prep_w_k(const float* __restrict__ wqkv, const float* __restrict__ wout,
                         short* __restrict__ wqkvT, short* __restrict__ woutT) {
  int id = blockIdx.x * 256 + threadIdx.x;
  if (id < 786432) {
    const int k = id / 1536, c = id - k * 1536;
    wqkvT[(size_t)c * 512 + k] = f2bf(wqkv[id]);
  } else {
    id -= 786432;
    const int k = id >> 9, c = id & 511;
    woutT[(size_t)c * 512 + k] = f2bf(wout[id]);
  }
}

// ---------------- V transpose: Vt[bh][dh][key] ----------------
__global__ __launch_bounds__(256) void vt_k(const short* __restrict__ qkv, short* __restrict__ vt) {
  __shared__ short t[64][136];
  const int bh = blockIdx.y;          // b*4+h
  const int b = bh >> 2, h = bh & 3;
  const int k0 = blockIdx.x * 64;
  const int tid = threadIdx.x;
  const int key = tid >> 2, part = tid & 3;
  const short* src = qkv + ((size_t)(b * NN + k0 + key) * 1536 + 1024 + h * 128 + part * 32);
  #pragma unroll
  for (int i = 0; i < 4; ++i) {
    short8 v = *reinterpret_cast<const short8*>(src + i * 8);
    #pragma unroll
    for (int j = 0; j < 8; ++j) t[key][part * 32 + i * 8 + j] = v[j];
  }
  __syncthreads();
  const int dh = tid >> 1, half = tid & 1;
  short* dst = vt + ((size_t)(bh * 128 + dh) * NN + k0 + half * 32);
  #pragma unroll
  for (int i = 0; i < 4; ++i) {
    short8 o;
    #pragma unroll
    for (int j = 0; j < 8; ++j) o[j] = t[half * 32 + i * 8 + j][dh];
    *reinterpret_cast<short8*>(dst + i * 8) = o;
  }
}

// ---------------- BMx128 tile GEMM (2-phase dbuf): C = A[M,512] * Bt[N,512]^T ----------------
template<int BM, int NT, bool BF16OUT>
__global__ __launch_bounds__(256) void gemm_bt_k(
    const short* __restrict__ A, const short* __restrict__ Bt, void* __restrict__ C) {
  constexpr int K = 512;
  constexpr int ABYTES = BM * 128;
  __shared__ char lds[2 * ABYTES + 32768];
  constexpr int nTiles = NT / 128;
  const int m0 = (blockIdx.x / nTiles) * BM;
  const int n0 = (blockIdx.x % nTiles) * 128;
  const int tid = threadIdx.x, wave = tid >> 6, lane = tid & 63;
  const int wm = wave >> 1, wn = wave & 1;
  const int lg = lane >> 4, li = lane & 15;
  constexpr int MT = BM / 32;
  f32x4 acc[MT][4] = {};

  auto stage = [&](int buf, int kt) {
    #pragma unroll
    for (int t = 0; t < BM / 32; ++t) {
      const int dbase = t * 4096 + wave * 1024;
      const int m = (dbase >> 7) + (lane >> 3);
      const int cs = ((lane & 7) * 16) ^ ((m & 7) << 4);
      async_cp16((const char*)A + ((size_t)(m0 + m) * K + kt * 64) * 2 + cs,
                 lds + buf * ABYTES + dbase);
    }
    #pragma unroll
    for (int t = 0; t < 4; ++t) {
      const int dbase = t * 4096 + wave * 1024;
      const int n = (dbase >> 7) + (lane >> 3);
      const int cs = ((lane & 7) * 16) ^ ((n & 7) << 4);
      async_cp16((const char*)Bt + ((size_t)(n0 + n) * K + kt * 64) * 2 + cs,
                 lds + 2 * ABYTES + buf * 16384 + dbase);
    }
  };

  stage(0, 0);
  __syncthreads();
  for (int kt = 0; kt < 8; ++kt) {
    const int cur = kt & 1;
    if (kt < 7) stage(cur ^ 1, kt + 1);
    const char* Al = lds + cur * ABYTES;
    const char* Bl = lds + 2 * ABYTES + cur * 16384;
    #pragma unroll
    for (int ks = 0; ks < 2; ++ks) {
      const int kb = ks * 64 + lg * 16;
      short8 af[MT], bfr[4];
      #pragma unroll
      for (int t = 0; t < MT; ++t) {
        const int r = wm * (BM / 2) + t * 16 + li;
        af[t] = *reinterpret_cast<const short8*>(Al + r * 128 + (kb ^ ((r & 7) << 4)));
      }
      #pragma unroll
      for (int t = 0; t < 4; ++t) {
        const int c = wn * 64 + t * 16 + li;
        bfr[t] = *reinterpret_cast<const short8*>(Bl + c * 128 + (kb ^ ((c & 7) << 4)));
      }
      #pragma unroll
      for (int mt = 0; mt < MT; ++mt)
        #pragma unroll
        for (int nt = 0; nt < 4; ++nt)
          acc[mt][nt] = __builtin_amdgcn_mfma_f32_16x16x32_bf16(af[mt], bfr[nt], acc[mt][nt], 0, 0, 0);
    }
    __syncthreads();
  }
  #pragma unroll
  for (int mt = 0; mt < MT; ++mt) {
    #pragma unroll
    for (int nt = 0; nt < 4; ++nt) {
      const int row = m0 + wm * (BM / 2) + mt * 16 + lg * 4;
      const int col = n0 + wn * 64 + nt * 16 + li;
      #pragma unroll
      for (int r = 0; r < 4; ++r) {
        if (BF16OUT)
          reinterpret_cast<short*>(C)[(size_t)(row + r) * NT + col] = f2bf(acc[mt][nt][r]);
        else
          reinterpret_cast<float*>(C)[(size_t)(row + r) * NT + col] = acc[mt][nt][r];
      }
    }
  }
}

// ---------------- fused flash attention + entropy ----------------
__global__ __launch_bounds__(256) void attn_k(
    const short* __restrict__ qkv, const short* __restrict__ vt,
    const float* __restrict__ alibi, short* __restrict__ ao, float* __restrict__ ent) {
  __shared__ char lds[73728];   // K dbuf 32K | V dbuf 32K | P 4x2K
  const int qt = blockIdx.x, bh = blockIdx.y;
  const int b = bh >> 2, h = bh & 3;
  const int tid = threadIdx.x, wave = tid >> 6, lane = tid & 63;
  const int lg = lane >> 4, li = lane & 15;
  char* const Pbase = lds + 65536 + wave * 2048;

  const int qrow = qt * 64 + wave * 16 + li;
  const char* qptr = (const char*)qkv + ((size_t)(b * NN + qrow) * 1536 + h * 128) * 2;
  short8 qf[4];
  #pragma unroll
  for (int kq = 0; kq < 4; ++kq)
    qf[kq] = *reinterpret_cast<const short8*>(qptr + kq * 64 + lg * 16);

  f32x4 oacc[8] = {};
  float mrow = -INFINITY, lrow = 0.f, trow = 0.f;
  const float* arow = alibi + (size_t)(b * NN + qrow) * NN;

  auto stageK = [&](int buf, int kt) {
    #pragma unroll
    for (int i = 0; i < 4; ++i) {
      const int chunk = wave * 4 + i;
      const int row = chunk * 4 + (lane >> 4);                       // key 0..63
      const int cs = ((lane & 15) * 16) ^ ((row & 15) << 4);
      async_cp16((const char*)qkv + ((size_t)(b * NN + kt * 64 + row) * 1536 + 512 + h * 128) * 2 + cs,
                 lds + buf * 16384 + chunk * 1024);
    }
  };
  auto stageV = [&](int buf, int kt) {
    #pragma unroll
    for (int i = 0; i < 4; ++i) {
      const int chunk = wave * 4 + i;
      const int row = chunk * 8 + (lane >> 3);                       // dh 0..127
      const int cs = ((lane & 7) * 16) ^ ((row & 7) << 4);
      async_cp16((const char*)vt + ((size_t)(bh * 128 + row) * NN + kt * 64) * 2 + cs,
                 lds + 32768 + buf * 16384 + chunk * 1024);
    }
  };
  auto loadA = [&](int kt, float4* ab) {
    #pragma unroll
    for (int ct = 0; ct < 4; ++ct)
      ab[ct] = *reinterpret_cast<const float4*>(arow + kt * 64 + ct * 16 + lg * 4);
  };

  float4 abE[4], abO[4];
  stageK(0, 0); stageV(0, 0);
  loadA(0, abE); loadA(1, abO);
  __syncthreads();

  #pragma unroll 1
  for (int kt2 = 0; kt2 < 32; kt2 += 2) {
    #pragma unroll
    for (int par = 0; par < 2; ++par) {
      const int kt = kt2 + par;
      const int cur = par, nxt = par ^ 1;
      float4* const ab = par ? abO : abE;
      if (kt < 31) { stageK(nxt, kt + 1); stageV(nxt, kt + 1); }

      // QK^T swapped: D[key][q], q = li lane-local
      f32x4 sacc[4] = {};
      const char* Kl = lds + cur * 16384;
      #pragma unroll
      for (int ct = 0; ct < 4; ++ct) {
        const int key = ct * 16 + li;
        #pragma unroll
        for (int kq = 0; kq < 4; ++kq) {
          short8 kf = *reinterpret_cast<const short8*>(
              Kl + key * 256 + ((kq * 64 + lg * 16) ^ ((key & 15) << 4)));
          sacc[ct] = __builtin_amdgcn_mfma_f32_16x16x32_bf16(kf, qf[kq], sacc[ct], 0, 0, 0);
        }
      }
      float sv[4][4], p[4][4];
      #pragma unroll
      for (int ct = 0; ct < 4; ++ct) {
        sv[ct][0] = fmaf(sacc[ct][0], SCALE, ab[ct].x);
        sv[ct][1] = fmaf(sacc[ct][1], SCALE, ab[ct].y);
        sv[ct][2] = fmaf(sacc[ct][2], SCALE, ab[ct].z);
        sv[ct][3] = fmaf(sacc[ct][3], SCALE, ab[ct].w);
      }
      if (kt + 2 < 32) loadA(kt + 2, ab);            // depth-2 alibi prefetch (same parity regs)

      float mx = sv[0][0];
      #pragma unroll
      for (int ct = 0; ct < 4; ++ct)
        #pragma unroll
        for (int r = 0; r < 4; ++r) mx = fmaxf(mx, sv[ct][r]);
      mx = fmaxf(mx, __shfl_xor(mx, 16));
      mx = fmaxf(mx, __shfl_xor(mx, 32));
      const bool resc = !__all(mx <= mrow + 8.0f);   // defer-max
      float newm = mrow, fsc = 1.0f;
      if (resc) { newm = fmaxf(mrow, mx); fsc = __expf(mrow - newm); }
      float lsum = 0.f, tsum = 0.f;
      #pragma unroll
      for (int ct = 0; ct < 4; ++ct)
        #pragma unroll
        for (int r = 0; r < 4; ++r) {
          p[ct][r] = __expf(sv[ct][r] - newm);
          lsum += p[ct][r];
          tsum = fmaf(p[ct][r], sv[ct][r], tsum);
        }
      lsum += __shfl_xor(lsum, 16); lsum += __shfl_xor(lsum, 32);
      tsum += __shfl_xor(tsum, 16); tsum += __shfl_xor(tsum, 32);
      if (resc) {
        lrow = lrow * fsc + lsum; trow = trow * fsc + tsum; mrow = newm;
        #pragma unroll
        for (int nt = 0; nt < 8; ++nt) oacc[nt] *= fsc;
      } else { lrow += lsum; trow += tsum; }

      #pragma unroll
      for (int ct = 0; ct < 4; ++ct) {
        short4_t pw;
        #pragma unroll
        for (int r = 0; r < 4; ++r) pw[r] = f2bf(p[ct][r]);
        *reinterpret_cast<short4_t*>(Pbase + li * 128 + ((ct * 32 + lg * 8) ^ ((li & 7) << 4))) = pw;
      }
      const char* Vl = lds + 32768 + cur * 16384;
      #pragma unroll
      for (int ks = 0; ks < 2; ++ks) {
        const int kb = ks * 64 + lg * 16;
        short8 pa = *reinterpret_cast<const short8*>(Pbase + li * 128 + (kb ^ ((li & 7) << 4)));
        #pragma unroll
        for (int nt = 0; nt < 8; ++nt) {
          const int dh = nt * 16 + li;
          short8 vb = *reinterpret_cast<const short8*>(Vl + dh * 128 + (kb ^ ((dh & 7) << 4)));
          oacc[nt] = __builtin_amdgcn_mfma_f32_16x16x32_bf16(vb, pa, oacc[nt], 0, 0, 0);
        }
      }
      __syncthreads();
    }
  }

  const float invl = 1.0f / lrow;
  #pragma unroll
  for (int nt = 0; nt < 8; ++nt) {
    short4_t ow;
    #pragma unroll
    for (int r = 0; r < 4; ++r) ow[r] = f2bf(oacc[nt][r] * invl);
    *reinterpret_cast<short4_t*>(ao + (size_t)(b * NN + qrow) * DD + h * 128 + nt * 16 + lg * 4) = ow;
  }
  float e = (lg == 0) ? (mrow + logf(lrow) - trow * invl) : 0.f;
  #pragma unroll
  for (int m = 1; m < 64; m <<= 1) e += __shfl_xor(e, m);
  if (lane == 0) atomicAdd(ent, e * ENT_SCALE);
}

extern "C" void kernel_launch(void* const* d_in, const int* in_sizes, int n_in,
                              void* d_out, int out_size, void* d_ws, size_t ws_size,
                              hipStream_t stream) {
  const float* x     = (const float*)d_in[0];
  const float* alibi = (const float*)d_in[1];
  const float* gamma = (const float*)d_in[2];
  const float* beta  = (const float*)d_in[3];
  const float* lnw   = (const float*)d_in[4];
  const float* lnb   = (const float*)d_in[5];
  const float* wqkv  = (const float*)d_in[6];
  const float* wout  = (const float*)d_in[7];
  float* out = (float*)d_out;

  char* ws = (char*)d_ws;
  short* xn    = (short*)(ws);                       // 8 MB  [0, 8M)
  short* wqkvT = (short*)(ws + 8388608);             // 1.5 MB
  short* woutT = (short*)(ws + 9961472);             // 0.5 MB
  short* qkv   = (short*)(ws + 10485760);            // 24 MB [10M, 34M)
  short* vt    = (short*)(ws + 35651584);            // 8 MB  [34M, 42M)
  short* ao    = (short*)(ws);                       // reuse xn region

  hipMemsetAsync(out + 4194304, 0, 4, stream);       // zero entropy accumulator
  ln_film_k<<<2048, 256, 0, stream>>>(x, gamma, beta, lnw, lnb, xn);
  prep_w_k<<<4096, 256, 0, stream>>>(wqkv, wout, wqkvT, woutT);
  gemm_bt_k<64, 1536, true><<<128 * 12, 256, 0, stream>>>(xn, wqkvT, qkv);
  vt_k<<<dim3(32, 16), 256, 0, stream>>>(qkv, vt);
  attn_k<<<dim3(32, 16), 256, 0, stream>>>(qkv, vt, alibi, ao, out + 4194304);
  gemm_bt_k<64, 512, false><<<128 * 4, 256, 0, stream>>>(ao, woutT, out);
}

// Round 4
// 243.134 us; speedup vs baseline: 1.2468x; 1.0161x over previous
//
#include <hip/hip_runtime.h>
#include <hip/hip_bf16.h>

typedef __attribute__((ext_vector_type(8))) short short8;
typedef __attribute__((ext_vector_type(4))) short short4_t;
typedef __attribute__((ext_vector_type(4))) float f32x4;

static constexpr int NN = 2048, DD = 512;
static constexpr float SCALE = 0.088388347648318447f;   // 128^-0.5
static constexpr float ENT_SCALE = 0.1f / 32768.0f;     // mean over b*h*n rows * SPARSITY_WEIGHT

__device__ __forceinline__ short f2bf(float f) {
  __hip_bfloat16 h = __float2bfloat16(f);
  return *reinterpret_cast<short*>(&h);
}

__device__ __forceinline__ void async_cp16(const void* g, void* l) {
  __builtin_amdgcn_global_load_lds((const __attribute__((address_space(1))) void*)g,
                                   (__attribute__((address_space(3))) void*)l, 16, 0, 0);
}

// ---------------- LN + FiLM -> bf16 ----------------
__global__ __launch_bounds__(256) void ln_film_k(
    const float* __restrict__ x, const float* __restrict__ gamma,
    const float* __restrict__ beta, const float* __restrict__ lnw,
    const float* __restrict__ lnb, short* __restrict__ xn) {
  const int wave = threadIdx.x >> 6, lane = threadIdx.x & 63;
  const int row = blockIdx.x * 4 + wave;   // 0..8191
  const int b = row >> 11;
  const float4* xr = reinterpret_cast<const float4*>(x + (size_t)row * DD);
  float4 u = xr[lane * 2], v = xr[lane * 2 + 1];
  float s  = u.x + u.y + u.z + u.w + v.x + v.y + v.z + v.w;
  float ss = u.x*u.x + u.y*u.y + u.z*u.z + u.w*u.w + v.x*v.x + v.y*v.y + v.z*v.z + v.w*v.w;
  #pragma unroll
  for (int m = 1; m < 64; m <<= 1) { s += __shfl_xor(s, m); ss += __shfl_xor(ss, m); }
  const float mu = s * (1.0f / DD);
  const float rs = rsqrtf(ss * (1.0f / DD) - mu * mu + 1e-5f);
  const int c0 = lane * 8;
  float vals[8] = {u.x,u.y,u.z,u.w,v.x,v.y,v.z,v.w};
  short8 o;
  #pragma unroll
  for (int i = 0; i < 8; ++i) {
    const int c = c0 + i;
    const float t = (vals[i] - mu) * rs * lnw[c] + lnb[c];
    o[i] = f2bf(gamma[b * DD + c] * t + beta[b * DD + c]);
  }
  *reinterpret_cast<short8*>(xn + (size_t)row * DD + c0) = o;
}

// ---------------- weight transposes, coalesced both sides ----------------
__global__ __launch_bounds__(256) void prep_w_k(
    const float* __restrict__ wqkv, const float* __restrict__ wout,
    short* __restrict__ wqkvT, short* __restrict__ woutT) {
  const int id = blockIdx.x;
  const float* src; short* dst; int C, k0, c0;
  if (id < 192) { src = wqkv; dst = wqkvT; C = 1536; k0 = (id / 24) * 64; c0 = (id % 24) * 64; }
  else { const int i2 = id - 192; src = wout; dst = woutT; C = 512; k0 = (i2 >> 3) * 64; c0 = (i2 & 7) * 64; }
  const int c  = c0 + (threadIdx.x & 63);
  const int kb = k0 + (threadIdx.x >> 6) * 16;
  short8 o0, o1;
  #pragma unroll
  for (int j = 0; j < 8; ++j) o0[j] = f2bf(src[(size_t)(kb + j) * C + c]);
  #pragma unroll
  for (int j = 0; j < 8; ++j) o1[j] = f2bf(src[(size_t)(kb + 8 + j) * C + c]);
  *reinterpret_cast<short8*>(dst + (size_t)c * 512 + kb)     = o0;
  *reinterpret_cast<short8*>(dst + (size_t)c * 512 + kb + 8) = o1;
}

// ---------------- V transpose: Vt[bh][dh][key] ----------------
__global__ __launch_bounds__(256) void vt_k(const short* __restrict__ qkv, short* __restrict__ vt) {
  __shared__ short t[64][136];
  const int bh = blockIdx.y;          // b*4+h
  const int b = bh >> 2, h = bh & 3;
  const int k0 = blockIdx.x * 64;
  const int tid = threadIdx.x;
  const int key = tid >> 2, part = tid & 3;
  const short* src = qkv + ((size_t)(b * NN + k0 + key) * 1536 + 1024 + h * 128 + part * 32);
  #pragma unroll
  for (int i = 0; i < 4; ++i) {
    short8 v = *reinterpret_cast<const short8*>(src + i * 8);
    #pragma unroll
    for (int j = 0; j < 8; ++j) t[key][part * 32 + i * 8 + j] = v[j];
  }
  __syncthreads();
  const int dh = tid >> 1, half = tid & 1;
  short* dst = vt + ((size_t)(bh * 128 + dh) * NN + k0 + half * 32);
  #pragma unroll
  for (int i = 0; i < 4; ++i) {
    short8 o;
    #pragma unroll
    for (int j = 0; j < 8; ++j) o[j] = t[half * 32 + i * 8 + j][dh];
    *reinterpret_cast<short8*>(dst + i * 8) = o;
  }
}

// ---------------- BMx128 tile GEMM (counted-vmcnt dbuf): C = A[M,512] * Bt[N,512]^T ----------------
template<int BM, int NT, bool BF16OUT>
__global__ __launch_bounds__(256) void gemm_bt_k(
    const short* __restrict__ A, const short* __restrict__ Bt, void* __restrict__ C) {
  constexpr int K = 512;
  constexpr int ABYTES = BM * 128;
  __shared__ char lds[2 * ABYTES + 32768];
  constexpr int nTiles = NT / 128;
  const int m0 = (blockIdx.x / nTiles) * BM;
  const int n0 = (blockIdx.x % nTiles) * 128;
  const int tid = threadIdx.x, wave = tid >> 6, lane = tid & 63;
  const int wm = wave >> 1, wn = wave & 1;
  const int lg = lane >> 4, li = lane & 15;
  constexpr int MT = BM / 32;
  f32x4 acc[MT][4] = {};

  auto stage = [&](int buf, int kt) {
    #pragma unroll
    for (int t = 0; t < BM / 32; ++t) {
      const int dbase = t * 4096 + wave * 1024;
      const int m = (dbase >> 7) + (lane >> 3);
      const int cs = ((lane & 7) * 16) ^ ((m & 7) << 4);
      async_cp16((const char*)A + ((size_t)(m0 + m) * K + kt * 64) * 2 + cs,
                 lds + buf * ABYTES + dbase);
    }
    #pragma unroll
    for (int t = 0; t < 4; ++t) {
      const int dbase = t * 4096 + wave * 1024;
      const int n = (dbase >> 7) + (lane >> 3);
      const int cs = ((lane & 7) * 16) ^ ((n & 7) << 4);
      async_cp16((const char*)Bt + ((size_t)(n0 + n) * K + kt * 64) * 2 + cs,
                 lds + 2 * ABYTES + buf * 16384 + dbase);
    }
  };

  stage(0, 0);
  for (int kt = 0; kt < 8; ++kt) {
    const int cur = kt & 1;
    if (kt < 7) stage(cur ^ 1, kt + 1);
    __builtin_amdgcn_sched_barrier(0);
    if (kt < 7) {
      if constexpr (BM == 128) asm volatile("s_waitcnt vmcnt(8)" ::: "memory");
      else                     asm volatile("s_waitcnt vmcnt(6)" ::: "memory");
    } else {
      asm volatile("s_waitcnt vmcnt(0)" ::: "memory");
    }
    __builtin_amdgcn_s_barrier();
    __builtin_amdgcn_sched_barrier(0);
    const char* Al = lds + cur * ABYTES;
    const char* Bl = lds + 2 * ABYTES + cur * 16384;
    #pragma unroll
    for (int ks = 0; ks < 2; ++ks) {
      const int kb = ks * 64 + lg * 16;
      short8 af[MT], bfr[4];
      #pragma unroll
      for (int t = 0; t < MT; ++t) {
        const int r = wm * (BM / 2) + t * 16 + li;
        af[t] = *reinterpret_cast<const short8*>(Al + r * 128 + (kb ^ ((r & 7) << 4)));
      }
      #pragma unroll
      for (int t = 0; t < 4; ++t) {
        const int c = wn * 64 + t * 16 + li;
        bfr[t] = *reinterpret_cast<const short8*>(Bl + c * 128 + (kb ^ ((c & 7) << 4)));
      }
      __builtin_amdgcn_s_setprio(1);
      #pragma unroll
      for (int mt = 0; mt < MT; ++mt)
        #pragma unroll
        for (int nt = 0; nt < 4; ++nt)
          acc[mt][nt] = __builtin_amdgcn_mfma_f32_16x16x32_bf16(af[mt], bfr[nt], acc[mt][nt], 0, 0, 0);
      __builtin_amdgcn_s_setprio(0);
    }
    __builtin_amdgcn_sched_barrier(0);
    __builtin_amdgcn_s_barrier();
  }
  #pragma unroll
  for (int mt = 0; mt < MT; ++mt) {
    #pragma unroll
    for (int nt = 0; nt < 4; ++nt) {
      const int row = m0 + wm * (BM / 2) + mt * 16 + lg * 4;
      const int col = n0 + wn * 64 + nt * 16 + li;
      #pragma unroll
      for (int r = 0; r < 4; ++r) {
        if (BF16OUT)
          reinterpret_cast<short*>(C)[(size_t)(row + r) * NT + col] = f2bf(acc[mt][nt][r]);
        else
          reinterpret_cast<float*>(C)[(size_t)(row + r) * NT + col] = acc[mt][nt][r];
      }
    }
  }
}

// ---------------- fused flash attention + entropy (counted-vmcnt pipeline) ----------------
__global__ __launch_bounds__(256) void attn_k(
    const short* __restrict__ qkv, const short* __restrict__ vt,
    const float* __restrict__ alibi, short* __restrict__ ao, float* __restrict__ ent) {
  __shared__ char lds[73728];   // K dbuf 32K | V dbuf 32K | P 4x2K
  const int qt = blockIdx.x, bh = blockIdx.y;
  const int b = bh >> 2, h = bh & 3;
  const int tid = threadIdx.x, wave = tid >> 6, lane = tid & 63;
  const int lg = lane >> 4, li = lane & 15;
  char* const Pbase = lds + 65536 + wave * 2048;

  const int qrow = qt * 64 + wave * 16 + li;
  const char* qptr = (const char*)qkv + ((size_t)(b * NN + qrow) * 1536 + h * 128) * 2;
  short8 qf[4];
  #pragma unroll
  for (int kq = 0; kq < 4; ++kq)
    qf[kq] = *reinterpret_cast<const short8*>(qptr + kq * 64 + lg * 16);

  f32x4 oacc[8] = {};
  float mrow = -INFINITY, lrow = 0.f, trow = 0.f;
  const float* arow = alibi + (size_t)(b * NN + qrow) * NN;

  auto stageK = [&](int buf, int kt) {
    #pragma unroll
    for (int i = 0; i < 4; ++i) {
      const int chunk = wave * 4 + i;
      const int row = chunk * 4 + (lane >> 4);                       // key 0..63
      const int cs = ((lane & 15) * 16) ^ ((row & 15) << 4);
      async_cp16((const char*)qkv + ((size_t)(b * NN + kt * 64 + row) * 1536 + 512 + h * 128) * 2 + cs,
                 lds + buf * 16384 + chunk * 1024);
    }
  };
  auto stageV = [&](int buf, int kt) {
    #pragma unroll
    for (int i = 0; i < 4; ++i) {
      const int chunk = wave * 4 + i;
      const int row = chunk * 8 + (lane >> 3);                       // dh 0..127
      const int cs = ((lane & 7) * 16) ^ ((row & 7) << 4);
      async_cp16((const char*)vt + ((size_t)(bh * 128 + row) * NN + kt * 64) * 2 + cs,
                 lds + 32768 + buf * 16384 + chunk * 1024);
    }
  };
  auto loadA = [&](int kt, float4* ab) {
    #pragma unroll
    for (int ct = 0; ct < 4; ++ct)
      ab[ct] = *reinterpret_cast<const float4*>(arow + kt * 64 + ct * 16 + lg * 4);
  };

  float4 abE[4], abO[4];
  stageK(0, 0); stageV(0, 0);       // 8 loads
  loadA(0, abE); loadA(1, abO);     // 8 loads

  #pragma unroll 1
  for (int kt2 = 0; kt2 < 32; kt2 += 2) {
    #pragma unroll
    for (int par = 0; par < 2; ++par) {
      const int kt = kt2 + par;
      const int cur = par, nxt = par ^ 1;
      float4* const ab = par ? abO : abE;
      // issue next tile's 8 global_load_lds (stays in flight across barriers)
      if (kt < 31) { stageK(nxt, kt + 1); stageV(nxt, kt + 1); }
      __builtin_amdgcn_sched_barrier(0);
      // per-iteration VMEM issue = 8 stage + 4 alibi = 12 -> vmcnt(12) == all
      // prior-iteration loads (incl. tile kt) complete, this iteration's in flight
      if (kt < 31) asm volatile("s_waitcnt vmcnt(12)" ::: "memory");
      else         asm volatile("s_waitcnt vmcnt(0)"  ::: "memory");
      __builtin_amdgcn_s_barrier();
      __builtin_amdgcn_sched_barrier(0);

      // QK^T swapped: D[key][q], q = li lane-local
      f32x4 sacc[4] = {};
      const char* Kl = lds + cur * 16384;
      __builtin_amdgcn_s_setprio(1);
      #pragma unroll
      for (int ct = 0; ct < 4; ++ct) {
        const int key = ct * 16 + li;
        #pragma unroll
        for (int kq = 0; kq < 4; ++kq) {
          short8 kf = *reinterpret_cast<const short8*>(
              Kl + key * 256 + ((kq * 64 + lg * 16) ^ ((key & 15) << 4)));
          sacc[ct] = __builtin_amdgcn_mfma_f32_16x16x32_bf16(kf, qf[kq], sacc[ct], 0, 0, 0);
        }
      }
      __builtin_amdgcn_s_setprio(0);

      float sv[4][4], p[4][4];
      #pragma unroll
      for (int ct = 0; ct < 4; ++ct) {
        sv[ct][0] = fmaf(sacc[ct][0], SCALE, ab[ct].x);
        sv[ct][1] = fmaf(sacc[ct][1], SCALE, ab[ct].y);
        sv[ct][2] = fmaf(sacc[ct][2], SCALE, ab[ct].z);
        sv[ct][3] = fmaf(sacc[ct][3], SCALE, ab[ct].w);
      }
      if (kt + 2 < 32) loadA(kt + 2, ab);            // depth-2 alibi prefetch (now survives barriers)

      float mx = sv[0][0];
      #pragma unroll
      for (int ct = 0; ct < 4; ++ct)
        #pragma unroll
        for (int r = 0; r < 4; ++r) mx = fmaxf(mx, sv[ct][r]);
      mx = fmaxf(mx, __shfl_xor(mx, 16));
      mx = fmaxf(mx, __shfl_xor(mx, 32));
      const bool resc = !__all(mx <= mrow + 8.0f);   // defer-max
      float newm = mrow, fsc = 1.0f;
      if (resc) { newm = fmaxf(mrow, mx); fsc = __expf(mrow - newm); }
      float lsum = 0.f, tsum = 0.f;
      #pragma unroll
      for (int ct = 0; ct < 4; ++ct)
        #pragma unroll
        for (int r = 0; r < 4; ++r) {
          p[ct][r] = __expf(sv[ct][r] - newm);
          lsum += p[ct][r];
          tsum = fmaf(p[ct][r], sv[ct][r], tsum);
        }
      lsum += __shfl_xor(lsum, 16); lsum += __shfl_xor(lsum, 32);
      tsum += __shfl_xor(tsum, 16); tsum += __shfl_xor(tsum, 32);
      if (resc) {
        lrow = lrow * fsc + lsum; trow = trow * fsc + tsum; mrow = newm;
        #pragma unroll
        for (int nt = 0; nt < 8; ++nt) oacc[nt] *= fsc;
      } else { lrow += lsum; trow += tsum; }

      #pragma unroll
      for (int ct = 0; ct < 4; ++ct) {
        short4_t pw;
        #pragma unroll
        for (int r = 0; r < 4; ++r) pw[r] = f2bf(p[ct][r]);
        *reinterpret_cast<short4_t*>(Pbase + li * 128 + ((ct * 32 + lg * 8) ^ ((li & 7) << 4))) = pw;
      }
      const char* Vl = lds + 32768 + cur * 16384;
      __builtin_amdgcn_s_setprio(1);
      #pragma unroll
      for (int ks = 0; ks < 2; ++ks) {
        const int kb = ks * 64 + lg * 16;
        short8 pa = *reinterpret_cast<const short8*>(Pbase + li * 128 + (kb ^ ((li & 7) << 4)));
        #pragma unroll
        for (int nt = 0; nt < 8; ++nt) {
          const int dh = nt * 16 + li;
          short8 vb = *reinterpret_cast<const short8*>(Vl + dh * 128 + (kb ^ ((dh & 7) << 4)));
          oacc[nt] = __builtin_amdgcn_mfma_f32_16x16x32_bf16(vb, pa, oacc[nt], 0, 0, 0);
        }
      }
      __builtin_amdgcn_s_setprio(0);
      __builtin_amdgcn_sched_barrier(0);
      __builtin_amdgcn_s_barrier();                  // WAR: compute(kt) done before stage(kt+2)
    }
  }

  const float invl = 1.0f / lrow;
  #pragma unroll
  for (int nt = 0; nt < 8; ++nt) {
    short4_t ow;
    #pragma unroll
    for (int r = 0; r < 4; ++r) ow[r] = f2bf(oacc[nt][r] * invl);
    *reinterpret_cast<short4_t*>(ao + (size_t)(b * NN + qrow) * DD + h * 128 + nt * 16 + lg * 4) = ow;
  }
  float e = (lg == 0) ? (mrow + logf(lrow) - trow * invl) : 0.f;
  #pragma unroll
  for (int m = 1; m < 64; m <<= 1) e += __shfl_xor(e, m);
  if (lane == 0) atomicAdd(ent, e * ENT_SCALE);
}

extern "C" void kernel_launch(void* const* d_in, const int* in_sizes, int n_in,
                              void* d_out, int out_size, void* d_ws, size_t ws_size,
                              hipStream_t stream) {
  const float* x     = (const float*)d_in[0];
  const float* alibi = (const float*)d_in[1];
  const float* gamma = (const float*)d_in[2];
  const float* beta  = (const float*)d_in[3];
  const float* lnw   = (const float*)d_in[4];
  const float* lnb   = (const float*)d_in[5];
  const float* wqkv  = (const float*)d_in[6];
  const float* wout  = (const float*)d_in[7];
  float* out = (float*)d_out;

  char* ws = (char*)d_ws;
  short* xn    = (short*)(ws);                       // 8 MB  [0, 8M)
  short* wqkvT = (short*)(ws + 8388608);             // 1.5 MB
  short* woutT = (short*)(ws + 9961472);             // 0.5 MB
  short* qkv   = (short*)(ws + 10485760);            // 24 MB [10M, 34M)
  short* vt    = (short*)(ws + 35651584);            // 8 MB  [34M, 42M)
  short* ao    = (short*)(ws);                       // reuse xn region

  hipMemsetAsync(out + 4194304, 0, 4, stream);       // zero entropy accumulator
  ln_film_k<<<2048, 256, 0, stream>>>(x, gamma, beta, lnw, lnb, xn);
  prep_w_k<<<256, 256, 0, stream>>>(wqkv, wout, wqkvT, woutT);
  gemm_bt_k<128, 1536, true><<<64 * 12, 256, 0, stream>>>(xn, wqkvT, qkv);
  vt_k<<<dim3(32, 16), 256, 0, stream>>>(qkv, vt);
  attn_k<<<dim3(32, 16), 256, 0, stream>>>(qkv, vt, alibi, ao, out + 4194304);
  gemm_bt_k<64, 512, false><<<128 * 4, 256, 0, stream>>>(ao, woutT, out);
}